// Round 12
// baseline (23984.854 us; speedup 1.0000x reference)
//
#include <hip/hip_runtime.h>

#define BDIM 128
#define TDIM 1024
#define HDIM 256
#define SLOT (BDIM*HDIM)
#define NWG_TOTAL 64              // 48 layer (3 x 16 j-slices) + 16 head

typedef unsigned long long u64;

// ws byte offsets
#define BAR_OFF   0u              // root cnt w0, epoch w32, leaf cnt w64+leaf*32 (2048 B)
#define HD_OFF    2048u           // u32 interleaved h digits (d1|d2<<16) [2 par][3 l][B][H] = 786432 B
#define HF2_OFF   788480u         // fp32 layer-2 h copy [2 par][B][H] = 262144 B
#define XF_OFF    1050624u        // fp32 x features [B][T][6] = 3145728 B
#define DONEF_OFF 4196352u        // fp32 done [B][T] = 524288 B
#define W5_OFF    4720640u        // fp32 {wh0,wi1,wh1,wi2,wh2} = 3932160 B
#define WI0F_OFF  8652800u        // fp32 wi0 (768x6) = 18432 B
#define BIAS_OFF  8671232u        // fp32 {bi0,bh0,bi1,bh1,bi2,bh2} = 18432 B
#define WFY_OFF   8689664u        // fp32 wfy (30x256) = 30720 B
#define BFY_OFF   8720384u
#define WFP_OFF   8720512u
#define BFP_OFF   8721536u
#define WS_NEEDED 8721552u
#define NZERO_U32 262656          // (2048 + 786432 + 262144)/4 — bar + hd + hf2

typedef __attribute__((ext_vector_type(8))) short bf16x8;
typedef __attribute__((ext_vector_type(4))) float f32x4;

static __device__ __forceinline__ unsigned short f2bf(float f) {
  union { float f; unsigned u; } v; v.f = f;
  unsigned r = v.u + 0x7fffu + ((v.u >> 16) & 1u);   // RNE
  return (unsigned short)(r >> 16);
}
static __device__ __forceinline__ float bf2f(unsigned short h) {
  union { unsigned u; float f; } v; v.u = ((unsigned)h) << 16;
  return v.f;
}
static __device__ __forceinline__ float sigm(float x) { return 1.f / (1.f + __expf(-x)); }
static __device__ __forceinline__ float tanha(float x) { return 1.f - 2.f / (1.f + __expf(2.f * x)); }

// relaxed agent atomics: write-through (no dirty L2) / inv-immune loads
static __device__ __forceinline__ void st_u32(unsigned* p, unsigned v) {
  __hip_atomic_store(p, v, __ATOMIC_RELAXED, __HIP_MEMORY_SCOPE_AGENT);
}
static __device__ __forceinline__ void st_f32(float* p, float v) {
  __hip_atomic_store(p, v, __ATOMIC_RELAXED, __HIP_MEMORY_SCOPE_AGENT);
}
static __device__ __forceinline__ u64 ld_u64(const u64* p) {
  return __hip_atomic_load((u64*)p, __ATOMIC_RELAXED, __HIP_MEMORY_SCOPE_AGENT);
}
// 4 u64 (8 interleaved u32) -> digit-1 frag and digit-2 frag
static __device__ __forceinline__ void ld_frag_pair(const u64* base, bf16x8& f1, bf16x8& f2) {
  union { u64 q; unsigned short s[4]; } a, b, c, d;
  a.q = ld_u64(base + 0); b.q = ld_u64(base + 1);
  c.q = ld_u64(base + 2); d.q = ld_u64(base + 3);
  f1 = (bf16x8){(short)a.s[0], (short)a.s[2], (short)b.s[0], (short)b.s[2],
                (short)c.s[0], (short)c.s[2], (short)d.s[0], (short)d.s[2]};
  f2 = (bf16x8){(short)a.s[1], (short)a.s[3], (short)b.s[1], (short)b.s[3],
                (short)c.s[1], (short)c.s[3], (short)d.s[1], (short)d.s[3]};
}

__global__ void diag_kernel(float* out, float code) {
  if (threadIdx.x == 0 && blockIdx.x == 0) out[0] = code;
}

// ---------- prep: fp32 inputs -> fp32 ws mirrors, zero bar+hd+hf2, x-features ----------
__global__ void prep_kernel(const float* __restrict__ rew, const float* __restrict__ done,
                            const float* __restrict__ gamma, const float* __restrict__ prob,
                            const float* __restrict__ y, const float* __restrict__ y1,
                            const float* __restrict__ w_e1, const float* __restrict__ b_e1,
                            const float* __restrict__ w_e2, const float* __restrict__ b_e2,
                            const float* __restrict__ wi0, const float* __restrict__ wh0,
                            const float* __restrict__ bi0, const float* __restrict__ bh0,
                            const float* __restrict__ wi1, const float* __restrict__ wh1,
                            const float* __restrict__ bi1, const float* __restrict__ bh1,
                            const float* __restrict__ wi2, const float* __restrict__ wh2,
                            const float* __restrict__ bi2, const float* __restrict__ bh2,
                            const float* __restrict__ wfy, const float* __restrict__ bfy,
                            const float* __restrict__ wfp, const float* __restrict__ bfp,
                            char* __restrict__ ws) {
  unsigned* zbase = (unsigned*)ws;
  float* w5    = (float*)(ws + W5_OFF);
  float* wi0f  = (float*)(ws + WI0F_OFF);
  float* bias  = (float*)(ws + BIAS_OFF);
  float* wfyf  = (float*)(ws + WFY_OFF);
  float* bfyf  = (float*)(ws + BFY_OFF);
  float* wfpf  = (float*)(ws + WFP_OFF);
  float* bfpf  = (float*)(ws + BFP_OFF);
  float* donef = (float*)(ws + DONEF_OFF);
  float* xfeat = (float*)(ws + XF_OFF);

  __shared__ float we1[480], be1[16], we2[16];
  __shared__ float be2s, gam;
  for (int i = threadIdx.x; i < 480; i += blockDim.x) we1[i] = w_e1[i];
  if (threadIdx.x < 16) { be1[threadIdx.x] = b_e1[threadIdx.x]; we2[threadIdx.x] = w_e2[threadIdx.x]; }
  if (threadIdx.x == 0) { be2s = b_e2[0]; gam = gamma[0]; }
  __syncthreads();
  const int gid = blockIdx.x * blockDim.x + threadIdx.x;
  const int stride = gridDim.x * blockDim.x;

  for (int i = gid; i < NZERO_U32; i += stride) zbase[i] = 0u;
  for (int i = gid; i < 196608; i += stride) {
    w5[i]              = wh0[i];
    w5[196608 + i]     = wi1[i];
    w5[2 * 196608 + i] = wh1[i];
    w5[3 * 196608 + i] = wi2[i];
    w5[4 * 196608 + i] = wh2[i];
  }
  for (int i = gid; i < 4608; i += stride) wi0f[i] = wi0[i];
  for (int i = gid; i < 768; i += stride) {
    bias[i]           = bi0[i];
    bias[768 + i]     = bh0[i];
    bias[2 * 768 + i] = bi1[i];
    bias[3 * 768 + i] = bh1[i];
    bias[4 * 768 + i] = bi2[i];
    bias[5 * 768 + i] = bh2[i];
  }
  for (int i = gid; i < 7680; i += stride) wfyf[i] = wfy[i];
  for (int i = gid; i < 30; i += stride) bfyf[i] = bfy[i];
  for (int i = gid; i < 256; i += stride) wfpf[i] = wfp[i];
  if (gid == 0) bfpf[0] = bfp[0];
  for (int i = gid; i < BDIM * TDIM; i += stride) donef[i] = done[i];

  for (int i = gid; i < BDIM * TDIM; i += stride) {   // i = b*T + t
    float yr[30], y1r[30];
    #pragma unroll
    for (int c = 0; c < 30; ++c) { yr[c] = y[(size_t)i * 30 + c]; y1r[c] = y1[(size_t)i * 30 + c]; }
    float a0 = 0.f, a1 = 0.f;
    #pragma unroll 4
    for (int jm = 0; jm < 16; ++jm) {
      float s0 = be1[jm], s1 = be1[jm];
      #pragma unroll
      for (int c = 0; c < 30; ++c) { float w = we1[jm * 30 + c]; s0 += yr[c] * w; s1 += y1r[c] * w; }
      a0 += fmaxf(s0, 0.f) * we2[jm];
      a1 += fmaxf(s1, 0.f) * we2[jm];
    }
    float* xr = xfeat + (size_t)i * 6;
    xr[0] = rew[i]; xr[1] = done[i]; xr[2] = gam;
    xr[3] = prob[i]; xr[4] = sigm(a0 + be2s); xr[5] = sigm(a1 + be2s);
  }
}

// ------------- two-level grid barrier (8 leaf cachelines + root; epoch-guarded) -------
__device__ __forceinline__ void gbar(unsigned* __restrict__ bar, unsigned next) {
  __syncthreads();
  if (threadIdx.x == 0) {
    const int leaf = blockIdx.x & 7;
    unsigned p = __hip_atomic_fetch_add(&bar[64 + leaf * 32], 1u, __ATOMIC_ACQ_REL, __HIP_MEMORY_SCOPE_AGENT);
    if (p == 7u) {
      unsigned r = __hip_atomic_fetch_add(&bar[0], 1u, __ATOMIC_ACQ_REL, __HIP_MEMORY_SCOPE_AGENT);
      if (r == 7u) {
        __hip_atomic_store(&bar[0], 0u, __ATOMIC_RELAXED, __HIP_MEMORY_SCOPE_AGENT);
        #pragma unroll
        for (int i = 0; i < 8; ++i)
          __hip_atomic_store(&bar[64 + i * 32], 0u, __ATOMIC_RELAXED, __HIP_MEMORY_SCOPE_AGENT);
        __hip_atomic_store(&bar[32], next, __ATOMIC_RELEASE, __HIP_MEMORY_SCOPE_AGENT);
      }
    }
    while (__hip_atomic_load(&bar[32], __ATOMIC_RELAXED, __HIP_MEMORY_SCOPE_AGENT) < next)
      __builtin_amdgcn_s_sleep(2);
    (void)__hip_atomic_load(&bar[32], __ATOMIC_ACQUIRE, __HIP_MEMORY_SCOPE_AGENT);
  }
  __syncthreads();
}

// ---------------- layer WG: MFMA, 2-digit W (VGPR/LDS) x 2-digit h (write-through u32) --
template <bool L0T>
__device__ __forceinline__ void layer_body(int l, int js, char* __restrict__ ws,
                                           char* __restrict__ ldsx) {
  unsigned* hd = (unsigned*)(ws + HD_OFF);
  float* hf2 = (float*)(ws + HF2_OFF);
  unsigned* bar = (unsigned*)(ws + BAR_OFF);
  const float* donef = (const float*)(ws + DONEF_OFF);
  const float* xfeat = (const float*)(ws + XF_OFF);
  const float* w5    = (const float*)(ws + W5_OFF);
  const float* wi0f  = (const float*)(ws + WI0F_OFF);
  const float* bias  = (const float*)(ws + BIAS_OFF);

  const int tid = threadIdx.x;
  const int wv = tid >> 6, lane = tid & 63, q = lane >> 4, jj = lane & 15;
  const int j = js * 16 + jj;

  const float* Wh = w5 + (l == 0 ? 0 : (l == 1 ? 2 : 4)) * 196608;
  const float* Wx = L0T ? (const float*)0 : w5 + (l == 1 ? 1 : 3) * 196608;
  const float* bi = bias + 2 * l * 768;
  const float* bh = bias + (2 * l + 1) * 768;
  const float bi_r = bi[j], bi_z = bi[256 + j], bi_n = bi[512 + j];
  const float bh_r = bh[j], bh_z = bh[256 + j], bh_n = bh[512 + j];

  // Wh -> VGPR digit frags
  bf16x8 Bh[3][2][8];
  #pragma unroll
  for (int g = 0; g < 3; ++g)
    #pragma unroll
    for (int it = 0; it < 8; ++it) {
      const float* src = Wh + (size_t)(g * 256 + j) * 256 + it * 32 + q * 8;
      #pragma unroll
      for (int e = 0; e < 8; ++e) {
        const float w = src[e];
        const unsigned short d1 = f2bf(w);
        const unsigned short d2 = f2bf(w - bf2f(d1));
        Bh[g][0][it][e] = (short)d1;
        Bh[g][1][it][e] = (short)d2;
      }
    }

  // Wx -> LDS digit frags (l>0)
  if (!L0T) {
    for (int idx = tid; idx < 12288; idx += 256) {
      const int row = idx >> 8, k = idx & 255;
      const int g = row >> 4, jr = row & 15;
      const float w = Wx[(size_t)(g * 256 + js * 16 + jr) * 256 + k];
      const unsigned short d1 = f2bf(w);
      const unsigned short d2 = f2bf(w - bf2f(d1));
      const int it = k >> 5, kk = k & 31;
      *(unsigned short*)(ldsx + ((g * 2 + 0) * 8 + it) * 1280 + jr * 80 + kk * 2) = d1;
      *(unsigned short*)(ldsx + ((g * 2 + 1) * 8 + it) * 1280 + jr * 80 + kk * 2) = d2;
    }
  }
  __syncthreads();

  float wx0[3][6];
  if (L0T) {
    #pragma unroll
    for (int g = 0; g < 3; ++g)
      #pragma unroll
      for (int c = 0; c < 6; ++c) wx0[g][c] = wi0f[(g * 256 + j) * 6 + c];
  }

  float hc[8];                     // WG-private fp32 carry: [mt*4+i] at (mC, j)
  #pragma unroll
  for (int i = 0; i < 8; ++i) hc[i] = 0.f;

  const int mA0 = (wv * 2) * 16 + jj;
  const f32x4 z4 = {0.f, 0.f, 0.f, 0.f};

  for (int k = 0; k <= 1026; ++k) {
    const int t = 1023 - k + l;
    if ((unsigned)t < 1024u) {
      const int pr = (k + 1) & 1, pw = k & 1;
      const u64* hh = (const u64*)(hd + (size_t)(pr * 3 + l) * SLOT);
      const u64* hx = L0T ? (const u64*)0 : (const u64*)(hd + (size_t)(pr * 3 + l - 1) * SLOT);
      unsigned* hdw = hd + (size_t)(pw * 3 + l) * SLOT;
      float* hf2w = hf2 + (size_t)pw * SLOT;

      f32x4 Ch[2][3], Cx[2][3];
      #pragma unroll
      for (int mt = 0; mt < 2; ++mt)
        #pragma unroll
        for (int g = 0; g < 3; ++g) { Ch[mt][g] = z4; Cx[mt][g] = z4; }

      #pragma unroll
      for (int it = 0; it < 8; ++it) {
        const int koff4 = it * 16 + q * 4;      // u64 offset within row (256 cols = 128 u64)
        bf16x8 a1[2], a2[2], x1[2], x2[2];
        #pragma unroll
        for (int mt = 0; mt < 2; ++mt) {
          const int mA = mA0 + mt * 16;
          ld_frag_pair(hh + (size_t)mA * 128 + koff4, a1[mt], a2[mt]);
          if (!L0T) ld_frag_pair(hx + (size_t)mA * 128 + koff4, x1[mt], x2[mt]);
        }
        #pragma unroll
        for (int g = 0; g < 3; ++g) {
          #pragma unroll
          for (int dig = 0; dig < 2; ++dig) {
            const bf16x8 wb = Bh[g][dig][it];
            #pragma unroll
            for (int mt = 0; mt < 2; ++mt) {
              Ch[mt][g] = __builtin_amdgcn_mfma_f32_16x16x32_bf16(a1[mt], wb, Ch[mt][g], 0, 0, 0);
              Ch[mt][g] = __builtin_amdgcn_mfma_f32_16x16x32_bf16(a2[mt], wb, Ch[mt][g], 0, 0, 0);
            }
            if (!L0T) {
              const bf16x8 xb = *(const bf16x8*)(ldsx + ((g * 2 + dig) * 8 + it) * 1280 + jj * 80 + q * 16);
              #pragma unroll
              for (int mt = 0; mt < 2; ++mt) {
                Cx[mt][g] = __builtin_amdgcn_mfma_f32_16x16x32_bf16(x1[mt], xb, Cx[mt][g], 0, 0, 0);
                Cx[mt][g] = __builtin_amdgcn_mfma_f32_16x16x32_bf16(x2[mt], xb, Cx[mt][g], 0, 0, 0);
              }
            }
          }
        }
      }

      // epilogue (verified formulas; C/D layout row=q*4+i, col=jj)
      #pragma unroll
      for (int mt = 0; mt < 2; ++mt) {
        #pragma unroll
        for (int i = 0; i < 4; ++i) {
          const int mC = (wv * 2 + mt) * 16 + q * 4 + i;
          const float s = 1.f - donef[mC * TDIM + t];
          float gxr, gxz, gxn;
          if (L0T) {
            const float* xr = xfeat + ((size_t)mC * TDIM + t) * 6;
            gxr = 0.f; gxz = 0.f; gxn = 0.f;
            #pragma unroll
            for (int c = 0; c < 6; ++c) {
              const float xv = xr[c];
              gxr += xv * wx0[0][c]; gxz += xv * wx0[1][c]; gxn += xv * wx0[2][c];
            }
          } else {
            gxr = Cx[mt][0][i]; gxz = Cx[mt][1][i]; gxn = Cx[mt][2][i];
          }
          const float r = sigm(gxr + bi_r + s * Ch[mt][0][i] + bh_r);
          const float z = sigm(gxz + bi_z + s * Ch[mt][1][i] + bh_z);
          const float n = tanha(gxn + bi_n + r * (s * Ch[mt][2][i] + bh_n));
          const float hp = hc[mt * 4 + i] * s;
          const float hv = (1.f - z) * n + z * hp;
          hc[mt * 4 + i] = hv;
          const unsigned short d1 = f2bf(hv);
          const unsigned short d2 = f2bf(hv - bf2f(d1));
          st_u32(hdw + (size_t)mC * 256 + j, (unsigned)d1 | ((unsigned)d2 << 16));
          if (l == 2) st_f32(hf2w + (size_t)mC * 256 + j, hv);
        }
      }
    }
    if (k < 1026) gbar(bar, (unsigned)(k + 1));
  }
}

// ---------------- head WGs (fp32; reads layer-2 fp32 copy via inv-immune u64 loads) ----
__device__ __forceinline__ void head_body(int hw, char* __restrict__ ws, float* __restrict__ out) {
  const float* hf2 = (const float*)(ws + HF2_OFF);
  unsigned* bar = (unsigned*)(ws + BAR_OFF);
  const float* wfy = (const float*)(ws + WFY_OFF);
  const float* bfy = (const float*)(ws + BFY_OFF);
  const float* wfp = (const float*)(ws + WFP_OFF);
  const float* bfp = (const float*)(ws + BFP_OFF);

  const int tid = threadIdx.x;
  const int d = tid & 31;           // 0..29 yo, 30 pi, 31 idle
  const int bb = tid >> 5;          // 0..7
  const int b = hw * 8 + bb;
  const bool act = d < 31;
  const float* wrow = (d < 30) ? (wfy + d * 256) : wfp;
  const float biasv = (d < 30) ? bfy[d] : bfp[0];

  for (int k = 0; k <= 1026; ++k) {
    const int t = 1026 - k;
    if ((unsigned)t < 1024u && act) {
      const int rp = (k + 1) & 1;
      const u64* h2q = (const u64*)(hf2 + (size_t)rp * SLOT + (size_t)b * 256);
      float a0 = 0.f, a1 = 0.f;
      #pragma unroll 8
      for (int kk = 0; kk < 128; kk += 2) {
        union { u64 q; float f[2]; } A, B;
        A.q = ld_u64(h2q + kk);
        B.q = ld_u64(h2q + kk + 1);
        a0 += A.f[0] * wrow[2 * kk] + A.f[1] * wrow[2 * kk + 1];
        a1 += B.f[0] * wrow[2 * kk + 2] + B.f[1] * wrow[2 * kk + 3];
      }
      const float acc = a0 + a1;
      if (d < 30) st_f32(out + BDIM * TDIM + ((size_t)b * TDIM + t) * 30 + d, sigm(acc + biasv));
      else        st_f32(out + (size_t)b * TDIM + t, acc + biasv);
    }
    if (k < 1026) gbar(bar, (unsigned)(k + 1));
  }
}

__global__ void __launch_bounds__(256, 1) gru_main(char* __restrict__ ws,
                                                   float* __restrict__ out) {
  __shared__ char ldsx[61440];
  const int bid = blockIdx.x;
  if (bid < 48) {
    const int l = bid >> 4;
    const int js = bid & 15;
    if (l == 0) layer_body<true>(l, js, ws, ldsx);
    else        layer_body<false>(l, js, ws, ldsx);
  } else {
    head_body(bid - 48, ws, out);
  }
}

extern "C" void kernel_launch(void* const* d_in, const int* in_sizes, int n_in,
                              void* d_out, int out_size, void* d_ws, size_t ws_size,
                              hipStream_t stream) {
  static const int EXP_SIZES[26] = {131072, 131072, 1, 131072, 3932160, 3932160,
                                    4608, 196608, 768, 768,
                                    196608, 196608, 768, 768,
                                    196608, 196608, 768, 768,
                                    7680, 30, 256, 1, 480, 16, 16, 1};
  float code = 0.f;
  if (n_in != 26) code = 900.f;
  if (code == 0.f) {
    for (int i = 0; i < 26; ++i)
      if (in_sizes[i] != EXP_SIZES[i]) { code = 100.f + 4.f * (float)i; break; }
  }
  if (code == 0.f && out_size != 4063232) code = 400.f;
  if (code == 0.f && ws_size < (size_t)WS_NEEDED) code = 300.f;
  if (code != 0.f) {
    diag_kernel<<<1, 64, 0, stream>>>((float*)d_out, code);
    return;
  }

  char* ws = (char*)d_ws;
  prep_kernel<<<512, 256, 0, stream>>>(
      (const float*)d_in[0], (const float*)d_in[1], (const float*)d_in[2],
      (const float*)d_in[3], (const float*)d_in[4], (const float*)d_in[5],
      (const float*)d_in[22], (const float*)d_in[23], (const float*)d_in[24], (const float*)d_in[25],
      (const float*)d_in[6], (const float*)d_in[7], (const float*)d_in[8], (const float*)d_in[9],
      (const float*)d_in[10], (const float*)d_in[11], (const float*)d_in[12], (const float*)d_in[13],
      (const float*)d_in[14], (const float*)d_in[15], (const float*)d_in[16], (const float*)d_in[17],
      (const float*)d_in[18], (const float*)d_in[19], (const float*)d_in[20], (const float*)d_in[21],
      ws);
  gru_main<<<NWG_TOTAL, 256, 0, stream>>>(ws, (float*)d_out);
}

// Round 13
// 18097.823 us; speedup vs baseline: 1.3253x; 1.3253x over previous
//
#include <hip/hip_runtime.h>

#define BDIM 128
#define TDIM 1024
#define HDIM 256
#define SLOT (BDIM*HDIM)
#define NWG_TOTAL 64              // 48 layer (3 x 16 j-slices) + 16 head

// ws byte offsets (total == R11's proven 9,245,840)
#define FLAGS_OFF 0u              // u32 flag per (group g<4, wg<16) at u32 idx (g*16+w)*8 (32B apart)
#define HD_OFF    2048u           // bf16 h digit planes [(l*3+par)*2+dig][B*H] = 18*65536 = 1179648 B
#define HF2_OFF   1181696u        // fp32 layer-2 h ring [3 par][B][H] = 393216 B
#define XF_OFF    1574912u        // fp32 x features [B][T][6] = 3145728 B
#define DONEF_OFF 4720640u        // fp32 done [B][T] = 524288 B
#define W5_OFF    5244928u        // fp32 {wh0,wi1,wh1,wi2,wh2} = 3932160 B
#define WI0F_OFF  9177088u        // fp32 wi0 (768x6) = 18432 B
#define BIAS_OFF  9195520u        // fp32 {bi0,bh0,bi1,bh1,bi2,bh2} = 18432 B
#define WFY_OFF   9213952u        // fp32 wfy (30x256) = 30720 B
#define BFY_OFF   9244672u
#define WFP_OFF   9244800u
#define BFP_OFF   9245824u
#define WS_NEEDED 9245840u
#define NZERO_U32 393728          // (2048 + 1179648 + 393216)/4 — flags + hd + hf2

typedef __attribute__((ext_vector_type(8))) short bf16x8;
typedef __attribute__((ext_vector_type(4))) float f32x4;

static __device__ __forceinline__ unsigned short f2bf(float f) {
  union { float f; unsigned u; } v; v.f = f;
  unsigned r = v.u + 0x7fffu + ((v.u >> 16) & 1u);   // RNE
  return (unsigned short)(r >> 16);
}
static __device__ __forceinline__ float bf2f(unsigned short h) {
  union { unsigned u; float f; } v; v.u = ((unsigned)h) << 16;
  return v.f;
}
static __device__ __forceinline__ float sigm(float x) { return 1.f / (1.f + __expf(-x)); }
static __device__ __forceinline__ float tanha(float x) { return 1.f - 2.f / (1.f + __expf(2.f * x)); }

// all 16 producer flags of group g >= target? (16 independent relaxed loads)
static __device__ __forceinline__ bool chk16(unsigned* fl, int g, int target) {
  if (target <= 0) return true;
  int mn = 0x7fffffff;
  #pragma unroll
  for (int w = 0; w < 16; ++w) {
    const int v = (int)__hip_atomic_load(fl + (g * 16 + w) * 8, __ATOMIC_RELAXED, __HIP_MEMORY_SCOPE_AGENT);
    mn = v < mn ? v : mn;
  }
  return mn >= target;
}
static __device__ __forceinline__ void post_flag(unsigned* fl, int g, int w, int s1) {
  __hip_atomic_store(fl + (g * 16 + w) * 8, (unsigned)s1, __ATOMIC_RELEASE, __HIP_MEMORY_SCOPE_AGENT);
}

__global__ void diag_kernel(float* out, float code) {
  if (threadIdx.x == 0 && blockIdx.x == 0) out[0] = code;
}

// ---------- prep: fp32 inputs -> fp32 ws mirrors, zero flags+h rings, x-features -------
__global__ void prep_kernel(const float* __restrict__ rew, const float* __restrict__ done,
                            const float* __restrict__ gamma, const float* __restrict__ prob,
                            const float* __restrict__ y, const float* __restrict__ y1,
                            const float* __restrict__ w_e1, const float* __restrict__ b_e1,
                            const float* __restrict__ w_e2, const float* __restrict__ b_e2,
                            const float* __restrict__ wi0, const float* __restrict__ wh0,
                            const float* __restrict__ bi0, const float* __restrict__ bh0,
                            const float* __restrict__ wi1, const float* __restrict__ wh1,
                            const float* __restrict__ bi1, const float* __restrict__ bh1,
                            const float* __restrict__ wi2, const float* __restrict__ wh2,
                            const float* __restrict__ bi2, const float* __restrict__ bh2,
                            const float* __restrict__ wfy, const float* __restrict__ bfy,
                            const float* __restrict__ wfp, const float* __restrict__ bfp,
                            char* __restrict__ ws) {
  unsigned* zbase = (unsigned*)ws;
  float* w5    = (float*)(ws + W5_OFF);
  float* wi0f  = (float*)(ws + WI0F_OFF);
  float* bias  = (float*)(ws + BIAS_OFF);
  float* wfyf  = (float*)(ws + WFY_OFF);
  float* bfyf  = (float*)(ws + BFY_OFF);
  float* wfpf  = (float*)(ws + WFP_OFF);
  float* bfpf  = (float*)(ws + BFP_OFF);
  float* donef = (float*)(ws + DONEF_OFF);
  float* xfeat = (float*)(ws + XF_OFF);

  __shared__ float we1[480], be1[16], we2[16];
  __shared__ float be2s, gam;
  for (int i = threadIdx.x; i < 480; i += blockDim.x) we1[i] = w_e1[i];
  if (threadIdx.x < 16) { be1[threadIdx.x] = b_e1[threadIdx.x]; we2[threadIdx.x] = w_e2[threadIdx.x]; }
  if (threadIdx.x == 0) { be2s = b_e2[0]; gam = gamma[0]; }
  __syncthreads();
  const int gid = blockIdx.x * blockDim.x + threadIdx.x;
  const int stride = gridDim.x * blockDim.x;

  for (int i = gid; i < NZERO_U32; i += stride) zbase[i] = 0u;
  for (int i = gid; i < 196608; i += stride) {
    w5[i]              = wh0[i];
    w5[196608 + i]     = wi1[i];
    w5[2 * 196608 + i] = wh1[i];
    w5[3 * 196608 + i] = wi2[i];
    w5[4 * 196608 + i] = wh2[i];
  }
  for (int i = gid; i < 4608; i += stride) wi0f[i] = wi0[i];
  for (int i = gid; i < 768; i += stride) {
    bias[i]           = bi0[i];
    bias[768 + i]     = bh0[i];
    bias[2 * 768 + i] = bi1[i];
    bias[3 * 768 + i] = bh1[i];
    bias[4 * 768 + i] = bi2[i];
    bias[5 * 768 + i] = bh2[i];
  }
  for (int i = gid; i < 7680; i += stride) wfyf[i] = wfy[i];
  for (int i = gid; i < 30; i += stride) bfyf[i] = bfy[i];
  for (int i = gid; i < 256; i += stride) wfpf[i] = wfp[i];
  if (gid == 0) bfpf[0] = bfp[0];
  for (int i = gid; i < BDIM * TDIM; i += stride) donef[i] = done[i];

  for (int i = gid; i < BDIM * TDIM; i += stride) {   // i = b*T + t
    float yr[30], y1r[30];
    #pragma unroll
    for (int c = 0; c < 30; ++c) { yr[c] = y[(size_t)i * 30 + c]; y1r[c] = y1[(size_t)i * 30 + c]; }
    float a0 = 0.f, a1 = 0.f;
    #pragma unroll 4
    for (int jm = 0; jm < 16; ++jm) {
      float s0 = be1[jm], s1 = be1[jm];
      #pragma unroll
      for (int c = 0; c < 30; ++c) { float w = we1[jm * 30 + c]; s0 += yr[c] * w; s1 += y1r[c] * w; }
      a0 += fmaxf(s0, 0.f) * we2[jm];
      a1 += fmaxf(s1, 0.f) * we2[jm];
    }
    float* xr = xfeat + (size_t)i * 6;
    xr[0] = rew[i]; xr[1] = done[i]; xr[2] = gam;
    xr[3] = prob[i]; xr[4] = sigm(a0 + be2s); xr[5] = sigm(a1 + be2s);
  }
}

// ---------------- layer WG: dataflow-synchronized MFMA step loop ----------------
// groups: 0=L0, 1=L1, 2=L2, 3=head. flag value = completed steps (s+1).
template <bool L0T>
__device__ __forceinline__ void layer_body(int l, int js, char* __restrict__ ws,
                                           char* __restrict__ ldsx) {
  unsigned short* hd = (unsigned short*)(ws + HD_OFF);
  float* hf2 = (float*)(ws + HF2_OFF);
  unsigned* fl = (unsigned*)(ws + FLAGS_OFF);
  const float* donef = (const float*)(ws + DONEF_OFF);
  const float* xfeat = (const float*)(ws + XF_OFF);
  const float* w5    = (const float*)(ws + W5_OFF);
  const float* wi0f  = (const float*)(ws + WI0F_OFF);
  const float* bias  = (const float*)(ws + BIAS_OFF);

  const int tid = threadIdx.x;
  const int wv = tid >> 6, lane = tid & 63, q = lane >> 4, jj = lane & 15;
  const int j = js * 16 + jj;

  const float* Wh = w5 + (l == 0 ? 0 : (l == 1 ? 2 : 4)) * 196608;
  const float* Wx = L0T ? (const float*)0 : w5 + (l == 1 ? 1 : 3) * 196608;
  const float* bi = bias + 2 * l * 768;
  const float* bh = bias + (2 * l + 1) * 768;
  const float bi_r = bi[j], bi_z = bi[256 + j], bi_n = bi[512 + j];
  const float bh_r = bh[j], bh_z = bh[256 + j], bh_n = bh[512 + j];

  // Wh -> VGPR digit frags
  bf16x8 Bh[3][2][8];
  #pragma unroll
  for (int g = 0; g < 3; ++g)
    #pragma unroll
    for (int it = 0; it < 8; ++it) {
      const float* src = Wh + (size_t)(g * 256 + j) * 256 + it * 32 + q * 8;
      #pragma unroll
      for (int e = 0; e < 8; ++e) {
        const float w = src[e];
        const unsigned short d1 = f2bf(w);
        const unsigned short d2 = f2bf(w - bf2f(d1));
        Bh[g][0][it][e] = (short)d1;
        Bh[g][1][it][e] = (short)d2;
      }
    }

  // Wx -> LDS digit frags (l>0)
  if (!L0T) {
    for (int idx = tid; idx < 12288; idx += 256) {
      const int row = idx >> 8, k = idx & 255;
      const int g = row >> 4, jr = row & 15;
      const float w = Wx[(size_t)(g * 256 + js * 16 + jr) * 256 + k];
      const unsigned short d1 = f2bf(w);
      const unsigned short d2 = f2bf(w - bf2f(d1));
      const int it = k >> 5, kk = k & 31;
      *(unsigned short*)(ldsx + ((g * 2 + 0) * 8 + it) * 1280 + jr * 80 + kk * 2) = d1;
      *(unsigned short*)(ldsx + ((g * 2 + 1) * 8 + it) * 1280 + jr * 80 + kk * 2) = d2;
    }
  }
  __syncthreads();

  float wx0[3][6];
  if (L0T) {
    #pragma unroll
    for (int g = 0; g < 3; ++g)
      #pragma unroll
      for (int c = 0; c < 6; ++c) wx0[g][c] = wi0f[(g * 256 + j) * 6 + c];
  }

  float hc[8];                     // WG-private fp32 carry
  #pragma unroll
  for (int i = 0; i < 8; ++i) hc[i] = 0.f;

  const int mA0 = (wv * 2) * 16 + jj;
  const f32x4 z4 = {0.f, 0.f, 0.f, 0.f};

  for (int s = 0; s < 1024; ++s) {
    const int t = 1023 - s;
    const int pc = s % 3, pp = (s + 2) % 3;

    // dataflow waits:
    //  own layer done s-1: flag[l] >= s
    //  L0: back-pressure flag[1] >= s-2
    //  L1: flag[0] >= s+1 (h0(s) ready), flag[2] >= s-2
    //  L2: flag[1] >= s+1, flag[3] >= s-2
    if (tid == 0) {
      for (;;) {
        bool ok = chk16(fl, l, s);
        if (L0T)          ok = ok && chk16(fl, 1, s - 2);
        else if (l == 1)  ok = ok && chk16(fl, 0, s + 1) && chk16(fl, 2, s - 2);
        else              ok = ok && chk16(fl, 1, s + 1) && chk16(fl, 3, s - 2);
        if (ok) break;
        __builtin_amdgcn_s_sleep(1);
      }
      (void)__hip_atomic_load(fl, __ATOMIC_ACQUIRE, __HIP_MEMORY_SCOPE_AGENT);
    }
    __syncthreads();

    const unsigned short* hh1 = hd + (size_t)((l * 3 + pp) * 2 + 0) * SLOT;
    const unsigned short* hh2 = hd + (size_t)((l * 3 + pp) * 2 + 1) * SLOT;
    const unsigned short* hx1 = L0T ? (const unsigned short*)0 : hd + (size_t)(((l - 1) * 3 + pc) * 2 + 0) * SLOT;
    const unsigned short* hx2 = L0T ? (const unsigned short*)0 : hd + (size_t)(((l - 1) * 3 + pc) * 2 + 1) * SLOT;
    unsigned short* hdw1 = hd + (size_t)((l * 3 + pc) * 2 + 0) * SLOT;
    unsigned short* hdw2 = hd + (size_t)((l * 3 + pc) * 2 + 1) * SLOT;
    float* hf2w = hf2 + (size_t)pc * SLOT;

    f32x4 Ch[2][3], Cx[2][3];
    #pragma unroll
    for (int mt = 0; mt < 2; ++mt)
      #pragma unroll
      for (int g = 0; g < 3; ++g) { Ch[mt][g] = z4; Cx[mt][g] = z4; }

    #pragma unroll
    for (int it = 0; it < 8; ++it) {
      const int koff = it * 32 + q * 8;
      bf16x8 a1[2], a2[2], x1[2], x2[2];
      #pragma unroll
      for (int mt = 0; mt < 2; ++mt) {
        const int mA = mA0 + mt * 16;
        a1[mt] = *(const bf16x8*)(hh1 + (size_t)mA * 256 + koff);
        a2[mt] = *(const bf16x8*)(hh2 + (size_t)mA * 256 + koff);
        if (!L0T) {
          x1[mt] = *(const bf16x8*)(hx1 + (size_t)mA * 256 + koff);
          x2[mt] = *(const bf16x8*)(hx2 + (size_t)mA * 256 + koff);
        }
      }
      #pragma unroll
      for (int g = 0; g < 3; ++g) {
        #pragma unroll
        for (int dig = 0; dig < 2; ++dig) {
          const bf16x8 wb = Bh[g][dig][it];
          #pragma unroll
          for (int mt = 0; mt < 2; ++mt) {
            Ch[mt][g] = __builtin_amdgcn_mfma_f32_16x16x32_bf16(a1[mt], wb, Ch[mt][g], 0, 0, 0);
            Ch[mt][g] = __builtin_amdgcn_mfma_f32_16x16x32_bf16(a2[mt], wb, Ch[mt][g], 0, 0, 0);
          }
          if (!L0T) {
            const bf16x8 xb = *(const bf16x8*)(ldsx + ((g * 2 + dig) * 8 + it) * 1280 + jj * 80 + q * 16);
            #pragma unroll
            for (int mt = 0; mt < 2; ++mt) {
              Cx[mt][g] = __builtin_amdgcn_mfma_f32_16x16x32_bf16(x1[mt], xb, Cx[mt][g], 0, 0, 0);
              Cx[mt][g] = __builtin_amdgcn_mfma_f32_16x16x32_bf16(x2[mt], xb, Cx[mt][g], 0, 0, 0);
            }
          }
        }
      }
    }

    // epilogue (verified; C/D layout row=q*4+i, col=jj)
    #pragma unroll
    for (int mt = 0; mt < 2; ++mt) {
      #pragma unroll
      for (int i = 0; i < 4; ++i) {
        const int mC = (wv * 2 + mt) * 16 + q * 4 + i;
        const float sF = 1.f - donef[mC * TDIM + t];
        float gxr, gxz, gxn;
        if (L0T) {
          const float* xr = xfeat + ((size_t)mC * TDIM + t) * 6;
          gxr = 0.f; gxz = 0.f; gxn = 0.f;
          #pragma unroll
          for (int c = 0; c < 6; ++c) {
            const float xv = xr[c];
            gxr += xv * wx0[0][c]; gxz += xv * wx0[1][c]; gxn += xv * wx0[2][c];
          }
        } else {
          gxr = Cx[mt][0][i]; gxz = Cx[mt][1][i]; gxn = Cx[mt][2][i];
        }
        const float r = sigm(gxr + bi_r + sF * Ch[mt][0][i] + bh_r);
        const float z = sigm(gxz + bi_z + sF * Ch[mt][1][i] + bh_z);
        const float n = tanha(gxn + bi_n + r * (sF * Ch[mt][2][i] + bh_n));
        const float hp = hc[mt * 4 + i] * sF;
        const float hv = (1.f - z) * n + z * hp;
        hc[mt * 4 + i] = hv;
        const unsigned short d1 = f2bf(hv);
        const unsigned short d2 = f2bf(hv - bf2f(d1));
        hdw1[(size_t)mC * 256 + j] = d1;
        hdw2[(size_t)mC * 256 + j] = d2;
        if (l == 2) hf2w[(size_t)mC * 256 + j] = hv;
      }
    }

    __syncthreads();   // drain all waves' stores (vmcnt(0) per wave)
    if (tid == 0) post_flag(fl, l, js, s + 1);   // release: wbl2 covers this CU's XCD L2
  }
}

// ---------------- head WGs (fp32; flag-driven) ----------------
__device__ __forceinline__ void head_body(int hw, char* __restrict__ ws, float* __restrict__ out) {
  const float* hf2 = (const float*)(ws + HF2_OFF);
  unsigned* fl = (unsigned*)(ws + FLAGS_OFF);
  const float* wfy = (const float*)(ws + WFY_OFF);
  const float* bfy = (const float*)(ws + BFY_OFF);
  const float* wfp = (const float*)(ws + WFP_OFF);
  const float* bfp = (const float*)(ws + BFP_OFF);

  const int tid = threadIdx.x;
  const int d = tid & 31;           // 0..29 yo, 30 pi, 31 idle
  const int bb = tid >> 5;          // 0..7
  const int b = hw * 8 + bb;
  const bool act = d < 31;
  const float* wrow = (d < 30) ? (wfy + d * 256) : wfp;
  const float biasv = (d < 30) ? bfy[d] : bfp[0];

  for (int s = 0; s < 1024; ++s) {
    const int t = 1023 - s;
    if (tid == 0) {
      while (!chk16(fl, 2, s + 1)) __builtin_amdgcn_s_sleep(1);
      (void)__hip_atomic_load(fl, __ATOMIC_ACQUIRE, __HIP_MEMORY_SCOPE_AGENT);
    }
    __syncthreads();
    if (act) {
      const float* h2 = hf2 + (size_t)(s % 3) * SLOT + (size_t)b * 256;
      float a0 = 0.f, a1 = 0.f;
      #pragma unroll 8
      for (int kk = 0; kk < 256; kk += 8) {
        const f32x4 h0 = *(const f32x4*)(h2 + kk);
        const f32x4 h1 = *(const f32x4*)(h2 + kk + 4);
        const f32x4 w0 = *(const f32x4*)(wrow + kk);
        const f32x4 w1 = *(const f32x4*)(wrow + kk + 4);
        a0 += h0[0]*w0[0] + h0[1]*w0[1] + h0[2]*w0[2] + h0[3]*w0[3];
        a1 += h1[0]*w1[0] + h1[1]*w1[1] + h1[2]*w1[2] + h1[3]*w1[3];
      }
      const float acc = a0 + a1;
      if (d < 30) out[BDIM * TDIM + ((size_t)b * TDIM + t) * 30 + d] = sigm(acc + biasv);
      else        out[(size_t)b * TDIM + t] = acc + biasv;
    }
    __syncthreads();   // ensure all waves' h2 loads retired before signaling consume-done
    if (tid == 0) post_flag(fl, 3, hw, s + 1);
  }
}

__global__ void __launch_bounds__(256, 1) gru_main(char* __restrict__ ws,
                                                   float* __restrict__ out) {
  __shared__ char ldsx[61440];
  const int bid = blockIdx.x;
  if (bid < 48) {
    const int l = bid >> 4;
    const int js = bid & 15;
    if (l == 0) layer_body<true>(l, js, ws, ldsx);
    else        layer_body<false>(l, js, ws, ldsx);
  } else {
    head_body(bid - 48, ws, out);
  }
}

extern "C" void kernel_launch(void* const* d_in, const int* in_sizes, int n_in,
                              void* d_out, int out_size, void* d_ws, size_t ws_size,
                              hipStream_t stream) {
  static const int EXP_SIZES[26] = {131072, 131072, 1, 131072, 3932160, 3932160,
                                    4608, 196608, 768, 768,
                                    196608, 196608, 768, 768,
                                    196608, 196608, 768, 768,
                                    7680, 30, 256, 1, 480, 16, 16, 1};
  float code = 0.f;
  if (n_in != 26) code = 900.f;
  if (code == 0.f) {
    for (int i = 0; i < 26; ++i)
      if (in_sizes[i] != EXP_SIZES[i]) { code = 100.f + 4.f * (float)i; break; }
  }
  if (code == 0.f && out_size != 4063232) code = 400.f;
  if (code == 0.f && ws_size < (size_t)WS_NEEDED) code = 300.f;
  if (code != 0.f) {
    diag_kernel<<<1, 64, 0, stream>>>((float*)d_out, code);
    return;
  }

  char* ws = (char*)d_ws;
  prep_kernel<<<512, 256, 0, stream>>>(
      (const float*)d_in[0], (const float*)d_in[1], (const float*)d_in[2],
      (const float*)d_in[3], (const float*)d_in[4], (const float*)d_in[5],
      (const float*)d_in[22], (const float*)d_in[23], (const float*)d_in[24], (const float*)d_in[25],
      (const float*)d_in[6], (const float*)d_in[7], (const float*)d_in[8], (const float*)d_in[9],
      (const float*)d_in[10], (const float*)d_in[11], (const float*)d_in[12], (const float*)d_in[13],
      (const float*)d_in[14], (const float*)d_in[15], (const float*)d_in[16], (const float*)d_in[17],
      (const float*)d_in[18], (const float*)d_in[19], (const float*)d_in[20], (const float*)d_in[21],
      ws);
  gru_main<<<NWG_TOTAL, 256, 0, stream>>>(ws, (float*)d_out);
}